// Round 10
// baseline (223.976 us; speedup 1.0000x reference)
//
#include <hip/hip_runtime.h>

#define NN   12288
#define EE   393216
#define WELL 128                // ELL slots per row (pow2; max degree ~64)
#define NELL (NN*WELL)
#define BG   16
#define FIN  15
#define FH1  32
#define FH2  64
#define NCL  11
#define BNEPS 1e-5f
#define NBANK 32

typedef unsigned long long u64;
static inline int cdiv(long a, long b){ return (int)((a + b - 1) / b); }

__device__ __forceinline__ int getIdx(const void* p, long i, int is64){
  return is64 ? (int)((const long long*)p)[i] : ((const int*)p)[i];
}

__device__ __forceinline__ float degOf(unsigned lo){
  return 1.0f + (float)lo * (1.0f/1048576.0f);
}

// ---- pre: zero deg_cnt + csp banks + embf; pad x -> xp[N][16]; detect width ----
__global__ void k_pre(u64* deg_cnt, float* csp1, float* csp2, float* csp3,
                      float* embf, float* xp, const float* x,
                      const void* ei, const void* batch, int* flags){
  int g = blockIdx.x*256 + threadIdx.x;
  if (g < NN){
    deg_cnt[g] = 0ull;
    float v[16];
    #pragma unroll
    for (int j = 0; j < 15; j++) v[j] = x[g*15 + j];
    v[15] = 0.f;
    float4* dst = (float4*)(xp + g*16);
    dst[0] = make_float4(v[0],  v[1],  v[2],  v[3]);
    dst[1] = make_float4(v[4],  v[5],  v[6],  v[7]);
    dst[2] = make_float4(v[8],  v[9],  v[10], v[11]);
    dst[3] = make_float4(v[12], v[13], v[14], v[15]);
  }
  if (g < NBANK*128){ csp1[g] = 0.f; csp2[g] = 0.f; csp3[g] = 0.f; }
  if (g < BG*64) embf[g] = 0.f;          // pool accumulates via atomicMax, vals >= 0
  if (blockIdx.x == 0 && threadIdx.x < 64){
    const int* a = (const int*)ei;
    unsigned long long m0 = __ballot(a[2*threadIdx.x + 1] == 0);
    const int* b = (const int*)batch;
    int j = 96*threadIdx.x;
    unsigned long long m1 = __ballot(b[2*j + 1] == 0);
    if (threadIdx.x == 0){
      flags[0] = (m0 == ~0ull) ? 1 : 0;
      flags[1] = (m1 == ~0ull) ? 1 : 0;
    }
  }
}

// ---- edge pass: ONE u64 atomic per edge; returned count = ELL slot.
// Slot packed to 4 B: col[13:0] | wfix[31:14] (w * 2^17). ----
__global__ void k_edge(const float* ea, const float* we, const float* bedg,
                       const void* ei, const int* flags, u64* deg_cnt,
                       unsigned* csr_p){
  int e = blockIdx.x*256 + threadIdx.x;
  if (e >= EE) return;
  int is64 = flags[0];
  float2 eav = ((const float2*)ea)[e];
  float z = eav.x*we[0] + eav.y*we[1] + bedg[0];
  float w = 1.0f/(1.0f + expf(-z));
  int r = getIdx(ei, e, is64);
  int c = getIdx(ei, (long)EE + e, is64);
  u64 add = (1ull << 32) | (u64)__float2uint_rn(w * 1048576.0f);
  u64 old = atomicAdd(&deg_cnt[r], add);
  int slot = (int)(old >> 32);
  if (slot < WELL){
    unsigned wfix = __float2uint_rn(w * 131072.0f);     // 18-bit fixed, w <= 1
    csr_p[((long)r << 7) + slot] = (unsigned)c | (wfix << 14);
  }
}

// ---- fix2: pre-scale w *= rsqrt(deg[col]) in the packed slots ----
__global__ void __launch_bounds__(256) k_fix2(const u64* __restrict__ deg_cnt,
                                              unsigned* __restrict__ csr_p){
  int row = blockIdx.x*4 + (threadIdx.x >> 6);
  int lane = threadIdx.x & 63;
  const unsigned* cl = (const unsigned*)deg_cnt;        // low words
  int n = (int)(deg_cnt[row] >> 32);
  n = n < WELL ? n : WELL;
  for (int s = lane; s < n; s += 64){
    long idx = ((long)row << 7) + s;
    unsigned v = csr_p[idx];
    int c = (int)(v & 16383u);
    float w = (float)(v >> 14) * (1.0f/131072.0f);
    w *= rsqrtf(degOf(cl[2*c]));
    csr_p[idx] = (unsigned)c | (__float2uint_rn(w * 131072.0f) << 14);
  }
}

// ---- unified GCN layer: FLOAT4 gather path. One float4 of features per lane
// (LPR = F/4 lanes per row), KS-way K-split over chunks of 8 slots, partials
// reduced in LDS. Optional BN+relu of the input on the fly (coeffs from csp
// banks). Dense epilogue restricted to fi < FUSE (pad columns excluded). ----
template<int F, int FUSE, int LPR, int KS, int FO, int APPLY_BN>
__global__ void __launch_bounds__(256) k_layerv(
    const float* __restrict__ Hin,
    const float* __restrict__ cspin, const float* __restrict__ gam,
    const float* __restrict__ bet,
    const float* __restrict__ W, const float* __restrict__ bias,
    const u64* __restrict__ deg_cnt, const unsigned* __restrict__ csr_p,
    float* __restrict__ Pout, float* __restrict__ csout){
  const int R = 256/(LPR*KS);              // rows per block
  __shared__ float At[R][F];
  __shared__ float4 Apart[256];
  __shared__ float lcs[FO], lcq[FO];
  __shared__ float lsc[64], lsh[64];
  int tid = threadIdx.x;
  if (tid < FO){ lcs[tid] = 0.f; lcq[tid] = 0.f; }
  if (APPLY_BN && tid < F){
    float s = 0.f, q = 0.f;
    #pragma unroll
    for (int b = 0; b < NBANK; b++){
      s += cspin[b*128 + tid];
      q += cspin[b*128 + 64 + tid];
    }
    float mu  = s*(1.0f/NN);
    float var = q*(1.0f/NN) - mu*mu;
    float sc = gam[tid]*rsqrtf(var + BNEPS);
    lsc[tid] = sc;
    lsh[tid] = bet[tid] - mu*sc;
  }
  __syncthreads();
  int fl = tid % LPR;                      // which float4 of the row
  int sub = tid / LPR;
  int kw = sub % KS, lr = sub / KS;
  int f0 = fl*4;
  float sc0 = 1.f, sc1 = 1.f, sc2 = 1.f, sc3 = 1.f;
  float sh0 = 0.f, sh1 = 0.f, sh2 = 0.f, sh3 = 0.f;
  if (APPLY_BN){
    sc0 = lsc[f0]; sc1 = lsc[f0+1]; sc2 = lsc[f0+2]; sc3 = lsc[f0+3];
    sh0 = lsh[f0]; sh1 = lsh[f0+1]; sh2 = lsh[f0+2]; sh3 = lsh[f0+3];
  }
  int row = blockIdx.x*R + lr;
  u64 dc = deg_cnt[row];
  float d = rsqrtf(degOf((unsigned)(dc & 0xffffffffull)));
  int n = (int)(dc >> 32);
  n = n < WELL ? n : WELL;
  const float4* __restrict__ Hin4 = (const float4*)Hin;
  float ax = 0.f, ay = 0.f, az = 0.f, aw = 0.f;
  if (kw == 0){                            // self loop
    float4 v = Hin4[row*LPR + fl];
    if (APPLY_BN){
      ax = d * fmaxf(v.x*sc0 + sh0, 0.f);
      ay = d * fmaxf(v.y*sc1 + sh1, 0.f);
      az = d * fmaxf(v.z*sc2 + sh2, 0.f);
      aw = d * fmaxf(v.w*sc3 + sh3, 0.f);
    } else {
      ax = d*v.x; ay = d*v.y; az = d*v.z; aw = d*v.w;
    }
  }
  int nch = (n + 7) >> 3;                  // chunks of 8 slots
  const uint4* pb = (const uint4*)(csr_p + ((long)row << 7));  // 32 uint4
  for (int ch = kw; ch < nch; ch += KS){
    const uint4* pc = pb + 2*ch;
    uint4 q0 = pc[0], q1 = pc[1];
    unsigned pv[8];
    pv[0]=q0.x; pv[1]=q0.y; pv[2]=q0.z; pv[3]=q0.w;
    pv[4]=q1.x; pv[5]=q1.y; pv[6]=q1.z; pv[7]=q1.w;
    int base = ch*8;
    if (base + 8 > n){                     // mask garbage tail slots -> w=0
      #pragma unroll
      for (int j = 0; j < 8; j++) if (base + j >= n) pv[j] = 0u;
    }
    float4 h4[8];
    #pragma unroll
    for (int j = 0; j < 8; j++)
      h4[j] = Hin4[(int)(pv[j] & 16383u)*LPR + fl];
    #pragma unroll
    for (int j = 0; j < 8; j++){
      float w = (float)(pv[j] >> 14) * (1.0f/131072.0f);
      float hx = h4[j].x, hy = h4[j].y, hz = h4[j].z, hw = h4[j].w;
      if (APPLY_BN){
        hx = fmaxf(hx*sc0 + sh0, 0.f);
        hy = fmaxf(hy*sc1 + sh1, 0.f);
        hz = fmaxf(hz*sc2 + sh2, 0.f);
        hw = fmaxf(hw*sc3 + sh3, 0.f);
      }
      ax += w*hx; ay += w*hy; az += w*hz; aw += w*hw;
    }
  }
  Apart[tid] = make_float4(ax, ay, az, aw);
  __syncthreads();
  if (kw == 0){
    #pragma unroll
    for (int k = 1; k < KS; k++){
      float4 p = Apart[tid + k*LPR];
      ax += p.x; ay += p.y; az += p.z; aw += p.w;
    }
    float4* atrow = (float4*)&At[lr][0];
    atrow[fl] = make_float4(d*ax, d*ay, d*az, d*aw);
  }
  __syncthreads();
  const int fo = tid % FO;                 // 256 % FO == 0
  float bb = bias[fo];
  for (int o = tid; o < R*FO; o += 256){
    int l = o / FO;
    float s = bb;
    #pragma unroll
    for (int fi = 0; fi < FUSE; fi++) s += At[l][fi] * W[fi*FO + fo];
    Pout[(blockIdx.x*R + l)*FO + fo] = s;
    atomicAdd(&lcs[fo], s);
    atomicAdd(&lcq[fo], s*s);
  }
  __syncthreads();
  if (tid < FO){
    int bank = blockIdx.x & (NBANK-1);
    atomicAdd(&csout[bank*128 + tid],      lcs[tid]);
    atomicAdd(&csout[bank*128 + 64 + tid], lcq[tid]);
  }
}

// ---- pool: 16 chunks per graph (256 blocks); inline BN3 (m starts at 0 so
// fmax realizes the relu). atomicMax on float bits (vals >= 0). ----
__global__ void k_pool(const float* P3, const float* csp, const float* gam,
                       const float* bet, const void* batch, const int* flags,
                       float* embf){
  __shared__ float lsc[64], lsh[64];
  if (threadIdx.x < 64){
    float s = 0.f, q = 0.f;
    #pragma unroll
    for (int b = 0; b < NBANK; b++){
      s += csp[b*128 + threadIdx.x];
      q += csp[b*128 + 64 + threadIdx.x];
    }
    float mu  = s*(1.0f/NN);
    float var = q*(1.0f/NN) - mu*mu;
    float sc = gam[threadIdx.x]*rsqrtf(var + BNEPS);
    lsc[threadIdx.x] = sc;
    lsh[threadIdx.x] = bet[threadIdx.x] - mu*sc;
  }
  __syncthreads();
  int is64 = flags[1];
  int b = blockIdx.x & 15, chunk = blockIdx.x >> 4;
  int lo = 0, hi = NN;
  while (lo < hi){ int m = (lo+hi)>>1; if (getIdx(batch, m, is64) < b) lo = m+1; else hi = m; }
  int start = lo;
  lo = start; hi = NN;
  while (lo < hi){ int m = (lo+hi)>>1; if (getIdx(batch, m, is64) < b+1) lo = m+1; else hi = m; }
  int end = lo;
  int f = threadIdx.x & 63, grp = threadIdx.x >> 6;
  float sc = lsc[f], sh = lsh[f];
  float m = 0.0f;
  for (int i = start + chunk*4 + grp; i < end; i += 64)
    m = fmaxf(m, P3[(long)i*FH2 + f]*sc + sh);
  __shared__ float shm[4][64];
  shm[grp][f] = m;
  __syncthreads();
  if (grp == 0){
    float v = fmaxf(fmaxf(shm[0][f], shm[1][f]), fmaxf(shm[2][f], shm[3][f]));
    atomicMax((int*)&embf[b*64 + f], __float_as_int(v));
  }
}

// ---- head fc1 + BN + relu: wave per column; block 0 also copies emb -> out ----
__global__ void __launch_bounds__(256) k_fcA(const float* embf, const float* wf1,
    const float* bf1, const float* gf1, const float* bef1, float* s1g, float* out){
  if (blockIdx.x == 0){
    #pragma unroll
    for (int i = 0; i < 4; i++)
      out[BG*NCL + i*256 + threadIdx.x] = embf[i*256 + threadIdx.x];
  }
  int c = blockIdx.x*4 + (threadIdx.x >> 6);
  int l = threadIdx.x & 63;
  float wcol = wf1[l*512 + c];
  float z[BG];
  #pragma unroll
  for (int r = 0; r < BG; r++){
    float v = embf[r*64 + l] * wcol;
    #pragma unroll
    for (int off = 32; off > 0; off >>= 1) v += __shfl_down(v, off);
    z[r] = v;                 // valid on lane 0
  }
  if (l == 0){
    float bb = bf1[c];
    float s = 0.f, q = 0.f;
    #pragma unroll
    for (int r = 0; r < BG; r++){ float zr = z[r] + bb; s += zr; q += zr*zr; }
    float mean = s*(1.f/BG), var = q*(1.f/BG) - mean*mean;
    float inv = rsqrtf(var + BNEPS);
    float gg = gf1[c], b2 = bef1[c];
    #pragma unroll
    for (int r = 0; r < BG; r++)
      s1g[r*512 + c] = fmaxf(gg*(z[r] + bb - mean)*inv + b2, 0.f);
  }
}

// ---- head fc2 + BN + relu: wave per column ----
__global__ void __launch_bounds__(256) k_fcB(const float* s1g, const float* wf2,
    const float* bf2, const float* gf2, const float* bef2, float* s2g){
  int c = blockIdx.x*4 + (threadIdx.x >> 6);
  int l = threadIdx.x & 63;
  float wreg[8];
  #pragma unroll
  for (int j = 0; j < 8; j++) wreg[j] = wf2[(l + 64*j)*256 + c];
  float z[BG];
  #pragma unroll
  for (int r = 0; r < BG; r++){
    float v = 0.f;
    #pragma unroll
    for (int j = 0; j < 8; j++) v += s1g[r*512 + l + 64*j] * wreg[j];
    #pragma unroll
    for (int off = 32; off > 0; off >>= 1) v += __shfl_down(v, off);
    z[r] = v;
  }
  if (l == 0){
    float bb = bf2[c];
    float s = 0.f, q = 0.f;
    #pragma unroll
    for (int r = 0; r < BG; r++){ float zr = z[r] + bb; s += zr; q += zr*zr; }
    float mean = s*(1.f/BG), var = q*(1.f/BG) - mean*mean;
    float inv = rsqrtf(var + BNEPS);
    float gg = gf2[c], b2 = bef2[c];
    #pragma unroll
    for (int r = 0; r < BG; r++)
      s2g[r*256 + c] = fmaxf(gg*(z[r] + bb - mean)*inv + b2, 0.f);
  }
}

// ---- head fc3 + log_softmax ----
__global__ void k_fc3(const float* s2g, const float* wf3, const float* bf3, float* out){
  __shared__ float s2[BG*256];
  __shared__ float sl[BG*NCL];
  int t = threadIdx.x;
  for (int i = t; i < BG*256; i += 256) s2[i] = s2g[i];
  __syncthreads();
  if (t < BG*NCL){
    int r = t / NCL, c = t - r*NCL;
    float s = bf3[c];
    for (int k = 0; k < 256; k++) s += s2[r*256 + k]*wf3[k*NCL + c];
    sl[t] = s;
  }
  __syncthreads();
  if (t < BG){
    float m = -1e30f;
    for (int c = 0; c < NCL; c++) m = fmaxf(m, sl[t*NCL + c]);
    float s = 0.f;
    for (int c = 0; c < NCL; c++) s += expf(sl[t*NCL + c] - m);
    float lg = logf(s) + m;
    for (int c = 0; c < NCL; c++) out[t*NCL + c] = sl[t*NCL + c] - lg;
  }
}

extern "C" void kernel_launch(void* const* d_in, const int* in_sizes, int n_in,
                              void* d_out, int out_size, void* d_ws, size_t ws_size,
                              hipStream_t stream){
  const float* x    = (const float*)d_in[0];
  const float* ea   = (const float*)d_in[1];
  const float* we   = (const float*)d_in[2];
  const float* bedg = (const float*)d_in[3];
  const float* w1   = (const float*)d_in[4];  const float* b1  = (const float*)d_in[5];
  const float* g1   = (const float*)d_in[6];  const float* be1 = (const float*)d_in[7];
  const float* w2   = (const float*)d_in[8];  const float* b2  = (const float*)d_in[9];
  const float* g2   = (const float*)d_in[10]; const float* be2 = (const float*)d_in[11];
  const float* w3   = (const float*)d_in[12]; const float* b3  = (const float*)d_in[13];
  const float* g3   = (const float*)d_in[14]; const float* be3 = (const float*)d_in[15];
  const float* wf1  = (const float*)d_in[16]; const float* bf1 = (const float*)d_in[17];
  const float* gf1  = (const float*)d_in[18]; const float* bef1= (const float*)d_in[19];
  const float* wf2  = (const float*)d_in[20]; const float* bf2 = (const float*)d_in[21];
  const float* gf2  = (const float*)d_in[22]; const float* bef2= (const float*)d_in[23];
  const float* wf3  = (const float*)d_in[24]; const float* bf3 = (const float*)d_in[25];
  const void* ei    = d_in[26];
  const void* batch = d_in[27];
  float* out = (float*)d_out;

  u64* wq = (u64*)d_ws;
  u64* deg_cnt = wq; wq += NN;
  unsigned* csr_p = (unsigned*)wq; wq += NELL/2;   // packed 4B slots
  float* ws = (float*)wq;
  float* xp    = ws; ws += NN*16;            // x padded to 16 cols
  float* P1    = ws; ws += NN*FH1;
  float* P2    = ws; ws += NN*FH2;
  float* P3    = ws; ws += NN*FH2;
  float* csp1  = ws; ws += NBANK*128;
  float* csp2  = ws; ws += NBANK*128;
  float* csp3  = ws; ws += NBANK*128;
  float* embf  = ws; ws += BG*64;
  float* s1g   = ws; ws += BG*512;
  float* s2g   = ws; ws += BG*256;
  int* flags   = (int*)ws;                   // [0]=ei64 [1]=batch64

  k_pre<<<48, 256, 0, stream>>>(deg_cnt, csp1, csp2, csp3, embf, xp, x,
                                ei, batch, flags);
  k_edge<<<cdiv(EE,256), 256, 0, stream>>>(ea, we, bedg, ei, flags, deg_cnt, csr_p);
  k_fix2<<<NN/4, 256, 0, stream>>>(deg_cnt, csr_p);

  // layer 1: xp(16,use 15) -> P1(32)  [float4 path, LPR=4, KS=8, 1536 blocks]
  k_layerv<16,FIN,4,8,FH1,0><<<NN/8, 256, 0, stream>>>(xp,
      nullptr, nullptr, nullptr, w1, b1, deg_cnt, csr_p, P1, csp1);
  // layer 2: BN1(P1)(32) -> P2(64)    [float4 path, LPR=8, KS=4, 1536 blocks]
  k_layerv<FH1,FH1,8,4,FH2,1><<<NN/8, 256, 0, stream>>>(P1, csp1, g1, be1,
      w2, b2, deg_cnt, csr_p, P2, csp2);
  // layer 3: BN2(P2)(64) -> P3(64)    [float4 path, LPR=16, KS=2, 1536 blocks]
  k_layerv<FH2,FH2,16,2,FH2,1><<<NN/8, 256, 0, stream>>>(P2, csp2, g2, be2,
      w3, b3, deg_cnt, csr_p, P3, csp3);

  k_pool<<<256, 256, 0, stream>>>(P3, csp3, g3, be3, batch, flags, embf);
  k_fcA<<<128, 256, 0, stream>>>(embf, wf1, bf1, gf1, bef1, s1g, out);
  k_fcB<<<64, 256, 0, stream>>>(s1g, wf2, bf2, gf2, bef2, s2g);
  k_fc3<<<1, 256, 0, stream>>>(s2g, wf3, bf3, out);
}

// Round 11
// 221.160 us; speedup vs baseline: 1.0127x; 1.0127x over previous
//
#include <hip/hip_runtime.h>

#define NN   12288
#define EE   393216
#define WELL 128                // ELL slots per row (pow2; max degree ~64)
#define NELL (NN*WELL)
#define BG   16
#define FIN  15
#define FH1  32
#define FH2  64
#define NCL  11
#define BNEPS 1e-5f
#define NBANK 32

typedef unsigned long long u64;
static inline int cdiv(long a, long b){ return (int)((a + b - 1) / b); }

__device__ __forceinline__ int getIdx(const void* p, long i, int is64){
  return is64 ? (int)((const long long*)p)[i] : ((const int*)p)[i];
}

__device__ __forceinline__ float degOf(unsigned lo){
  return 1.0f + (float)lo * (1.0f/1048576.0f);
}

// ---- pre: zero deg_cnt + csp banks + embf; pad x -> xp[N][16]; detect width ----
__global__ void k_pre(u64* deg_cnt, float* csp1, float* csp2, float* csp3,
                      float* embf, float* xp, const float* x,
                      const void* ei, const void* batch, int* flags){
  int g = blockIdx.x*256 + threadIdx.x;
  if (g < NN){
    deg_cnt[g] = 0ull;
    float v[16];
    #pragma unroll
    for (int j = 0; j < 15; j++) v[j] = x[g*15 + j];
    v[15] = 0.f;
    float4* dst = (float4*)(xp + g*16);
    dst[0] = make_float4(v[0],  v[1],  v[2],  v[3]);
    dst[1] = make_float4(v[4],  v[5],  v[6],  v[7]);
    dst[2] = make_float4(v[8],  v[9],  v[10], v[11]);
    dst[3] = make_float4(v[12], v[13], v[14], v[15]);
  }
  if (g < NBANK*128){ csp1[g] = 0.f; csp2[g] = 0.f; csp3[g] = 0.f; }
  if (g < BG*64) embf[g] = 0.f;          // pool accumulates via atomicMax, vals >= 0
  if (blockIdx.x == 0 && threadIdx.x < 64){
    const int* a = (const int*)ei;
    unsigned long long m0 = __ballot(a[2*threadIdx.x + 1] == 0);
    const int* b = (const int*)batch;
    int j = 96*threadIdx.x;
    unsigned long long m1 = __ballot(b[2*j + 1] == 0);
    if (threadIdx.x == 0){
      flags[0] = (m0 == ~0ull) ? 1 : 0;
      flags[1] = (m1 == ~0ull) ? 1 : 0;
    }
  }
}

// ---- edge pass: ONE u64 atomic per edge; returned count = ELL slot.
// Slot packed to 4 B: col[13:0] | wfix[31:14] (w * 2^17). ----
__global__ void k_edge(const float* ea, const float* we, const float* bedg,
                       const void* ei, const int* flags, u64* deg_cnt,
                       unsigned* csr_p){
  int e = blockIdx.x*256 + threadIdx.x;
  if (e >= EE) return;
  int is64 = flags[0];
  float2 eav = ((const float2*)ea)[e];
  float z = eav.x*we[0] + eav.y*we[1] + bedg[0];
  float w = 1.0f/(1.0f + expf(-z));
  int r = getIdx(ei, e, is64);
  int c = getIdx(ei, (long)EE + e, is64);
  u64 add = (1ull << 32) | (u64)__float2uint_rn(w * 1048576.0f);
  u64 old = atomicAdd(&deg_cnt[r], add);
  int slot = (int)(old >> 32);
  if (slot < WELL){
    unsigned wfix = __float2uint_rn(w * 131072.0f);     // 18-bit fixed, w <= 1
    csr_p[((long)r << 7) + slot] = (unsigned)c | (wfix << 14);
  }
}

// ---- fix2: pre-scale w *= rsqrt(deg[col]) in the packed slots ----
__global__ void __launch_bounds__(256) k_fix2(const u64* __restrict__ deg_cnt,
                                              unsigned* __restrict__ csr_p){
  int row = blockIdx.x*4 + (threadIdx.x >> 6);
  int lane = threadIdx.x & 63;
  const unsigned* cl = (const unsigned*)deg_cnt;        // low words
  int n = (int)(deg_cnt[row] >> 32);
  n = n < WELL ? n : WELL;
  for (int s = lane; s < n; s += 64){
    long idx = ((long)row << 7) + s;
    unsigned v = csr_p[idx];
    int c = (int)(v & 16383u);
    float w = (float)(v >> 14) * (1.0f/131072.0f);
    w *= rsqrtf(degOf(cl[2*c]));
    csr_p[idx] = (unsigned)c | (__float2uint_rn(w * 131072.0f) << 14);
  }
}

// ---- unified GCN layer: FLOAT4 gather path (LPR = F/4 lanes per row),
// KS-way K-split over chunks of 8 slots, LDS partial reduce.
// Slot loads double-buffered across rounds (overlap with gathers).
// Optional BN+relu of input on the fly. Epilogue reads At via float4
// (ds_read_b128, 1/4 the LDS instructions); fi < FUSE excludes pad cols. ----
template<int F, int FUSE, int LPR, int KS, int FO, int APPLY_BN>
__global__ void __launch_bounds__(256) k_layerv(
    const float* __restrict__ Hin,
    const float* __restrict__ cspin, const float* __restrict__ gam,
    const float* __restrict__ bet,
    const float* __restrict__ W, const float* __restrict__ bias,
    const u64* __restrict__ deg_cnt, const unsigned* __restrict__ csr_p,
    float* __restrict__ Pout, float* __restrict__ csout){
  const int R = 256/(LPR*KS);              // rows per block
  __shared__ __align__(16) float At[R][F];
  __shared__ float4 Apart[256];
  __shared__ float lcs[FO], lcq[FO];
  __shared__ float lsc[64], lsh[64];
  int tid = threadIdx.x;
  if (tid < FO){ lcs[tid] = 0.f; lcq[tid] = 0.f; }
  if (APPLY_BN && tid < F){
    float s = 0.f, q = 0.f;
    #pragma unroll
    for (int b = 0; b < NBANK; b++){
      s += cspin[b*128 + tid];
      q += cspin[b*128 + 64 + tid];
    }
    float mu  = s*(1.0f/NN);
    float var = q*(1.0f/NN) - mu*mu;
    float sc = gam[tid]*rsqrtf(var + BNEPS);
    lsc[tid] = sc;
    lsh[tid] = bet[tid] - mu*sc;
  }
  __syncthreads();
  int fl = tid % LPR;                      // which float4 of the row
  int sub = tid / LPR;
  int kw = sub % KS, lr = sub / KS;
  int f0 = fl*4;
  float sc0 = 1.f, sc1 = 1.f, sc2 = 1.f, sc3 = 1.f;
  float sh0 = 0.f, sh1 = 0.f, sh2 = 0.f, sh3 = 0.f;
  if (APPLY_BN){
    sc0 = lsc[f0]; sc1 = lsc[f0+1]; sc2 = lsc[f0+2]; sc3 = lsc[f0+3];
    sh0 = lsh[f0]; sh1 = lsh[f0+1]; sh2 = lsh[f0+2]; sh3 = lsh[f0+3];
  }
  int row = blockIdx.x*R + lr;
  u64 dc = deg_cnt[row];
  float d = rsqrtf(degOf((unsigned)(dc & 0xffffffffull)));
  int n = (int)(dc >> 32);
  n = n < WELL ? n : WELL;
  const float4* __restrict__ Hin4 = (const float4*)Hin;
  float ax = 0.f, ay = 0.f, az = 0.f, aw = 0.f;
  if (kw == 0){                            // self loop
    float4 v = Hin4[row*LPR + fl];
    if (APPLY_BN){
      ax = d * fmaxf(v.x*sc0 + sh0, 0.f);
      ay = d * fmaxf(v.y*sc1 + sh1, 0.f);
      az = d * fmaxf(v.z*sc2 + sh2, 0.f);
      aw = d * fmaxf(v.w*sc3 + sh3, 0.f);
    } else {
      ax = d*v.x; ay = d*v.y; az = d*v.z; aw = d*v.w;
    }
  }
  int nch = (n + 7) >> 3;                  // chunks of 8 slots
  const uint4* pb = (const uint4*)(csr_p + ((long)row << 7));  // 32 uint4
  int ch = kw;
  if (ch < nch){
    uint4 q0 = pb[2*ch], q1 = pb[2*ch+1];  // current round's slots
    while (true){
      int chn = ch + KS;
      bool more = (chn < nch);
      uint4 p0, p1;
      if (more){ p0 = pb[2*chn]; p1 = pb[2*chn+1]; }   // prefetch next round
      unsigned pv[8];
      pv[0]=q0.x; pv[1]=q0.y; pv[2]=q0.z; pv[3]=q0.w;
      pv[4]=q1.x; pv[5]=q1.y; pv[6]=q1.z; pv[7]=q1.w;
      int base = ch*8;
      if (base + 8 > n){                   // mask garbage tail slots -> w=0
        #pragma unroll
        for (int j = 0; j < 8; j++) if (base + j >= n) pv[j] = 0u;
      }
      float4 h4[8];
      #pragma unroll
      for (int j = 0; j < 8; j++)
        h4[j] = Hin4[(int)(pv[j] & 16383u)*LPR + fl];
      #pragma unroll
      for (int j = 0; j < 8; j++){
        float w = (float)(pv[j] >> 14) * (1.0f/131072.0f);
        float hx = h4[j].x, hy = h4[j].y, hz = h4[j].z, hw = h4[j].w;
        if (APPLY_BN){
          hx = fmaxf(hx*sc0 + sh0, 0.f);
          hy = fmaxf(hy*sc1 + sh1, 0.f);
          hz = fmaxf(hz*sc2 + sh2, 0.f);
          hw = fmaxf(hw*sc3 + sh3, 0.f);
        }
        ax += w*hx; ay += w*hy; az += w*hz; aw += w*hw;
      }
      if (!more) break;
      ch = chn; q0 = p0; q1 = p1;
    }
  }
  Apart[tid] = make_float4(ax, ay, az, aw);
  __syncthreads();
  if (kw == 0){
    #pragma unroll
    for (int k = 1; k < KS; k++){
      float4 p = Apart[tid + k*LPR];
      ax += p.x; ay += p.y; az += p.z; aw += p.w;
    }
    float4* atrow = (float4*)&At[lr][0];
    atrow[fl] = make_float4(d*ax, d*ay, d*az, d*aw);
  }
  __syncthreads();
  const int fo = tid % FO;                 // 256 % FO == 0
  float bb = bias[fo];
  for (int o = tid; o < R*FO; o += 256){
    int l = o / FO;
    float s = bb;
    const float4* at4 = (const float4*)&At[l][0];
    #pragma unroll
    for (int fi4 = 0; fi4 < FUSE/4; fi4++){
      float4 a = at4[fi4];
      s += a.x * W[(fi4*4 + 0)*FO + fo];
      s += a.y * W[(fi4*4 + 1)*FO + fo];
      s += a.z * W[(fi4*4 + 2)*FO + fo];
      s += a.w * W[(fi4*4 + 3)*FO + fo];
    }
    #pragma unroll
    for (int fi = (FUSE/4)*4; fi < FUSE; fi++)
      s += At[l][fi] * W[fi*FO + fo];
    Pout[(blockIdx.x*R + l)*FO + fo] = s;
    atomicAdd(&lcs[fo], s);
    atomicAdd(&lcq[fo], s*s);
  }
  __syncthreads();
  if (tid < FO){
    int bank = blockIdx.x & (NBANK-1);
    atomicAdd(&csout[bank*128 + tid],      lcs[tid]);
    atomicAdd(&csout[bank*128 + 64 + tid], lcq[tid]);
  }
}

// ---- pool: 16 chunks per graph (256 blocks); inline BN3 (m starts at 0 so
// fmax realizes the relu). atomicMax on float bits (vals >= 0). ----
__global__ void k_pool(const float* P3, const float* csp, const float* gam,
                       const float* bet, const void* batch, const int* flags,
                       float* embf){
  __shared__ float lsc[64], lsh[64];
  if (threadIdx.x < 64){
    float s = 0.f, q = 0.f;
    #pragma unroll
    for (int b = 0; b < NBANK; b++){
      s += csp[b*128 + threadIdx.x];
      q += csp[b*128 + 64 + threadIdx.x];
    }
    float mu  = s*(1.0f/NN);
    float var = q*(1.0f/NN) - mu*mu;
    float sc = gam[threadIdx.x]*rsqrtf(var + BNEPS);
    lsc[threadIdx.x] = sc;
    lsh[threadIdx.x] = bet[threadIdx.x] - mu*sc;
  }
  __syncthreads();
  int is64 = flags[1];
  int b = blockIdx.x & 15, chunk = blockIdx.x >> 4;
  int lo = 0, hi = NN;
  while (lo < hi){ int m = (lo+hi)>>1; if (getIdx(batch, m, is64) < b) lo = m+1; else hi = m; }
  int start = lo;
  lo = start; hi = NN;
  while (lo < hi){ int m = (lo+hi)>>1; if (getIdx(batch, m, is64) < b+1) lo = m+1; else hi = m; }
  int end = lo;
  int f = threadIdx.x & 63, grp = threadIdx.x >> 6;
  float sc = lsc[f], sh = lsh[f];
  float m = 0.0f;
  for (int i = start + chunk*4 + grp; i < end; i += 64)
    m = fmaxf(m, P3[(long)i*FH2 + f]*sc + sh);
  __shared__ float shm[4][64];
  shm[grp][f] = m;
  __syncthreads();
  if (grp == 0){
    float v = fmaxf(fmaxf(shm[0][f], shm[1][f]), fmaxf(shm[2][f], shm[3][f]));
    atomicMax((int*)&embf[b*64 + f], __float_as_int(v));
  }
}

// ---- head fc1 + BN + relu: wave per column; block 0 also copies emb -> out ----
__global__ void __launch_bounds__(256) k_fcA(const float* embf, const float* wf1,
    const float* bf1, const float* gf1, const float* bef1, float* s1g, float* out){
  if (blockIdx.x == 0){
    #pragma unroll
    for (int i = 0; i < 4; i++)
      out[BG*NCL + i*256 + threadIdx.x] = embf[i*256 + threadIdx.x];
  }
  int c = blockIdx.x*4 + (threadIdx.x >> 6);
  int l = threadIdx.x & 63;
  float wcol = wf1[l*512 + c];
  float z[BG];
  #pragma unroll
  for (int r = 0; r < BG; r++){
    float v = embf[r*64 + l] * wcol;
    #pragma unroll
    for (int off = 32; off > 0; off >>= 1) v += __shfl_down(v, off);
    z[r] = v;                 // valid on lane 0
  }
  if (l == 0){
    float bb = bf1[c];
    float s = 0.f, q = 0.f;
    #pragma unroll
    for (int r = 0; r < BG; r++){ float zr = z[r] + bb; s += zr; q += zr*zr; }
    float mean = s*(1.f/BG), var = q*(1.f/BG) - mean*mean;
    float inv = rsqrtf(var + BNEPS);
    float gg = gf1[c], b2 = bef1[c];
    #pragma unroll
    for (int r = 0; r < BG; r++)
      s1g[r*512 + c] = fmaxf(gg*(z[r] + bb - mean)*inv + b2, 0.f);
  }
}

// ---- head fc2 + BN + relu: wave per column ----
__global__ void __launch_bounds__(256) k_fcB(const float* s1g, const float* wf2,
    const float* bf2, const float* gf2, const float* bef2, float* s2g){
  int c = blockIdx.x*4 + (threadIdx.x >> 6);
  int l = threadIdx.x & 63;
  float wreg[8];
  #pragma unroll
  for (int j = 0; j < 8; j++) wreg[j] = wf2[(l + 64*j)*256 + c];
  float z[BG];
  #pragma unroll
  for (int r = 0; r < BG; r++){
    float v = 0.f;
    #pragma unroll
    for (int j = 0; j < 8; j++) v += s1g[r*512 + l + 64*j] * wreg[j];
    #pragma unroll
    for (int off = 32; off > 0; off >>= 1) v += __shfl_down(v, off);
    z[r] = v;
  }
  if (l == 0){
    float bb = bf2[c];
    float s = 0.f, q = 0.f;
    #pragma unroll
    for (int r = 0; r < BG; r++){ float zr = z[r] + bb; s += zr; q += zr*zr; }
    float mean = s*(1.f/BG), var = q*(1.f/BG) - mean*mean;
    float inv = rsqrtf(var + BNEPS);
    float gg = gf2[c], b2 = bef2[c];
    #pragma unroll
    for (int r = 0; r < BG; r++)
      s2g[r*256 + c] = fmaxf(gg*(z[r] + bb - mean)*inv + b2, 0.f);
  }
}

// ---- head fc3 + log_softmax ----
__global__ void k_fc3(const float* s2g, const float* wf3, const float* bf3, float* out){
  __shared__ float s2[BG*256];
  __shared__ float sl[BG*NCL];
  int t = threadIdx.x;
  for (int i = t; i < BG*256; i += 256) s2[i] = s2g[i];
  __syncthreads();
  if (t < BG*NCL){
    int r = t / NCL, c = t - r*NCL;
    float s = bf3[c];
    for (int k = 0; k < 256; k++) s += s2[r*256 + k]*wf3[k*NCL + c];
    sl[t] = s;
  }
  __syncthreads();
  if (t < BG){
    float m = -1e30f;
    for (int c = 0; c < NCL; c++) m = fmaxf(m, sl[t*NCL + c]);
    float s = 0.f;
    for (int c = 0; c < NCL; c++) s += expf(sl[t*NCL + c] - m);
    float lg = logf(s) + m;
    for (int c = 0; c < NCL; c++) out[t*NCL + c] = sl[t*NCL + c] - lg;
  }
}

extern "C" void kernel_launch(void* const* d_in, const int* in_sizes, int n_in,
                              void* d_out, int out_size, void* d_ws, size_t ws_size,
                              hipStream_t stream){
  const float* x    = (const float*)d_in[0];
  const float* ea   = (const float*)d_in[1];
  const float* we   = (const float*)d_in[2];
  const float* bedg = (const float*)d_in[3];
  const float* w1   = (const float*)d_in[4];  const float* b1  = (const float*)d_in[5];
  const float* g1   = (const float*)d_in[6];  const float* be1 = (const float*)d_in[7];
  const float* w2   = (const float*)d_in[8];  const float* b2  = (const float*)d_in[9];
  const float* g2   = (const float*)d_in[10]; const float* be2 = (const float*)d_in[11];
  const float* w3   = (const float*)d_in[12]; const float* b3  = (const float*)d_in[13];
  const float* g3   = (const float*)d_in[14]; const float* be3 = (const float*)d_in[15];
  const float* wf1  = (const float*)d_in[16]; const float* bf1 = (const float*)d_in[17];
  const float* gf1  = (const float*)d_in[18]; const float* bef1= (const float*)d_in[19];
  const float* wf2  = (const float*)d_in[20]; const float* bf2 = (const float*)d_in[21];
  const float* gf2  = (const float*)d_in[22]; const float* bef2= (const float*)d_in[23];
  const float* wf3  = (const float*)d_in[24]; const float* bf3 = (const float*)d_in[25];
  const void* ei    = d_in[26];
  const void* batch = d_in[27];
  float* out = (float*)d_out;

  u64* wq = (u64*)d_ws;
  u64* deg_cnt = wq; wq += NN;
  unsigned* csr_p = (unsigned*)wq; wq += NELL/2;   // packed 4B slots
  float* ws = (float*)wq;
  float* xp    = ws; ws += NN*16;            // x padded to 16 cols
  float* P1    = ws; ws += NN*FH1;
  float* P2    = ws; ws += NN*FH2;
  float* P3    = ws; ws += NN*FH2;
  float* csp1  = ws; ws += NBANK*128;
  float* csp2  = ws; ws += NBANK*128;
  float* csp3  = ws; ws += NBANK*128;
  float* embf  = ws; ws += BG*64;
  float* s1g   = ws; ws += BG*512;
  float* s2g   = ws; ws += BG*256;
  int* flags   = (int*)ws;                   // [0]=ei64 [1]=batch64

  k_pre<<<48, 256, 0, stream>>>(deg_cnt, csp1, csp2, csp3, embf, xp, x,
                                ei, batch, flags);
  k_edge<<<cdiv(EE,256), 256, 0, stream>>>(ea, we, bedg, ei, flags, deg_cnt, csr_p);
  k_fix2<<<NN/4, 256, 0, stream>>>(deg_cnt, csr_p);

  // layer 1: xp(16,use 15) -> P1(32)  [float4 path, LPR=4, KS=8, 1536 blocks]
  k_layerv<16,FIN,4,8,FH1,0><<<NN/8, 256, 0, stream>>>(xp,
      nullptr, nullptr, nullptr, w1, b1, deg_cnt, csr_p, P1, csp1);
  // layer 2: BN1(P1)(32) -> P2(64)    [float4 path, LPR=8, KS=4, 1536 blocks]
  k_layerv<FH1,FH1,8,4,FH2,1><<<NN/8, 256, 0, stream>>>(P1, csp1, g1, be1,
      w2, b2, deg_cnt, csr_p, P2, csp2);
  // layer 3: BN2(P2)(64) -> P3(64)    [float4 path, LPR=16, KS=2, 1536 blocks]
  k_layerv<FH2,FH2,16,2,FH2,1><<<NN/8, 256, 0, stream>>>(P2, csp2, g2, be2,
      w3, b3, deg_cnt, csr_p, P3, csp3);

  k_pool<<<256, 256, 0, stream>>>(P3, csp3, g3, be3, batch, flags, embf);
  k_fcA<<<128, 256, 0, stream>>>(embf, wf1, bf1, gf1, bef1, s1g, out);
  k_fcB<<<64, 256, 0, stream>>>(s1g, wf2, bf2, gf2, bef2, s2g);
  k_fc3<<<1, 256, 0, stream>>>(s2g, wf3, bf3, out);
}